// Round 3
// baseline (387.468 us; speedup 1.0000x reference)
//
#include <hip/hip_runtime.h>
#include <hip/hip_bf16.h>
#include <stdint.h>

// Attention block: x@Wqkv -> flash-attn (8 heads, d=64, n=2048, b=8) -> @Wout
// Strategy: bf16 MFMA (16x16x32) everywhere, fp32 accumulation.
// ws layout: xb | q | k | vT | ao | wqkvT | woutT   (all bf16)

#define NB 8
#define SEQ 2048
#define DIMM 512
#define HEADS 8
#define DHEAD 64
#define MTOT (NB * SEQ)  // 16384

typedef __attribute__((ext_vector_type(8))) short bf16x8;
typedef __attribute__((ext_vector_type(4))) float f32x4;

__device__ __forceinline__ ushort f2b(float f) {
  union { float f; uint32_t u; } c; c.f = f;
  return (ushort)((c.u + 0x7FFFu + ((c.u >> 16) & 1u)) >> 16);  // RNE
}

// ---------------- prep: fp32 -> bf16 (vectorized) ----------------
__global__ void cvt_bf16(const float* __restrict__ src, ushort* __restrict__ dst, int n8) {
  int i = blockIdx.x * blockDim.x + threadIdx.x;
  if (i >= n8) return;
  const float4* s = (const float4*)src;
  float4 a = s[2 * i], b = s[2 * i + 1];
  ushort o[8] = {f2b(a.x), f2b(a.y), f2b(a.z), f2b(a.w),
                 f2b(b.x), f2b(b.y), f2b(b.z), f2b(b.w)};
  *(uint4*)(dst + 8 * i) = *(const uint4*)o;
}

// ---------------- prep: fp32 [R][C] -> bf16 [C][R] (LDS tile transpose) ----------------
__global__ void cvt_transpose(const float* __restrict__ src, ushort* __restrict__ dst,
                              int R, int C) {
  __shared__ ushort tile[64][72];
  int nbc = C >> 6;
  int bc = blockIdx.x % nbc, br = blockIdx.x / nbc;
  int c0 = bc * 64, r0 = br * 64;
  #pragma unroll
  for (int p = 0; p < 16; ++p) {
    int e = p * 256 + threadIdx.x;
    int r = e >> 6, c = e & 63;
    tile[r][c] = f2b(src[(size_t)(r0 + r) * C + c0 + c]);
  }
  __syncthreads();
  #pragma unroll
  for (int p = 0; p < 16; ++p) {
    int e = p * 256 + threadIdx.x;
    int ct = e >> 6, rt = e & 63;
    dst[(size_t)(c0 + ct) * R + r0 + rt] = tile[rt][ct];
  }
}

// ---------------- GEMM core: C[128][128] per block, A[m][k], Bt[n][k], K=512 ----------------
// 4 waves in 2x2, each 64x64 = 4x4 frags of 16x16, BK=64.

__global__ __launch_bounds__(256) void gemm_qkv(
    const ushort* __restrict__ A, const ushort* __restrict__ Bt,
    ushort* __restrict__ qo, ushort* __restrict__ ko, ushort* __restrict__ vto) {
  __shared__ ushort As[128][72];
  __shared__ ushort Bs[128][72];
  const int tid = threadIdx.x;
  const int bn = blockIdx.x % 12, bm = blockIdx.x / 12;
  const int wid = tid >> 6, lane = tid & 63;
  const int wm = (wid >> 1) * 64, wn = (wid & 1) * 64;
  const int lr = lane & 15, lk = (lane >> 4) * 8;

  f32x4 acc[4][4] = {};
  const ushort* Ab = A + (size_t)(bm * 128) * DIMM;
  const ushort* Bb = Bt + (size_t)(bn * 128) * DIMM;

  for (int kt = 0; kt < DIMM; kt += 64) {
    __syncthreads();
    #pragma unroll
    for (int p = 0; p < 4; ++p) {
      int e = p * 256 + tid;
      int r = e >> 3, c8 = (e & 7) << 3;
      *(uint4*)&As[r][c8] = *(const uint4*)(Ab + (size_t)r * DIMM + kt + c8);
      *(uint4*)&Bs[r][c8] = *(const uint4*)(Bb + (size_t)r * DIMM + kt + c8);
    }
    __syncthreads();
    #pragma unroll
    for (int kk = 0; kk < 64; kk += 32) {
      bf16x8 af[4], bfr[4];
      #pragma unroll
      for (int i = 0; i < 4; ++i) af[i] = *(const bf16x8*)&As[wm + i * 16 + lr][kk + lk];
      #pragma unroll
      for (int j = 0; j < 4; ++j) bfr[j] = *(const bf16x8*)&Bs[wn + j * 16 + lr][kk + lk];
      #pragma unroll
      for (int i = 0; i < 4; ++i)
        #pragma unroll
        for (int j = 0; j < 4; ++j)
          acc[i][j] = __builtin_amdgcn_mfma_f32_16x16x32_bf16(af[i], bfr[j], acc[i][j], 0, 0, 0);
    }
  }

  const int rb = bm * 128 + wm + ((lane >> 4) << 2);
  const int cb = bn * 128 + wn + lr;
  #pragma unroll
  for (int i = 0; i < 4; ++i) {
    #pragma unroll
    for (int j = 0; j < 4; ++j) {
      int col = cb + j * 16;
      int t = col >> 9, h = (col >> 6) & 7, d = col & 63;
      f32x4 v = acc[i][j];
      #pragma unroll
      for (int e = 0; e < 4; ++e) {
        int row = rb + i * 16 + e;
        int b = row >> 11, n = row & 2047;
        float val = v[e];
        if (t == 0) {
          qo[(((size_t)b * HEADS + h) * SEQ + n) * DHEAD + d] = f2b(val * 0.125f);
        } else if (t == 1) {
          ko[(((size_t)b * HEADS + h) * SEQ + n) * DHEAD + d] = f2b(val);
        } else {
          vto[(((size_t)b * HEADS + h) * DHEAD + d) * SEQ + n] = f2b(val);  // V transposed
        }
      }
    }
  }
}

__global__ __launch_bounds__(256) void gemm_out(
    const ushort* __restrict__ A, const ushort* __restrict__ Bt, float* __restrict__ out) {
  __shared__ ushort As[128][72];
  __shared__ ushort Bs[128][72];
  const int tid = threadIdx.x;
  const int bn = blockIdx.x % 4, bm = blockIdx.x / 4;
  const int wid = tid >> 6, lane = tid & 63;
  const int wm = (wid >> 1) * 64, wn = (wid & 1) * 64;
  const int lr = lane & 15, lk = (lane >> 4) * 8;

  f32x4 acc[4][4] = {};
  const ushort* Ab = A + (size_t)(bm * 128) * DIMM;
  const ushort* Bb = Bt + (size_t)(bn * 128) * DIMM;

  for (int kt = 0; kt < DIMM; kt += 64) {
    __syncthreads();
    #pragma unroll
    for (int p = 0; p < 4; ++p) {
      int e = p * 256 + tid;
      int r = e >> 3, c8 = (e & 7) << 3;
      *(uint4*)&As[r][c8] = *(const uint4*)(Ab + (size_t)r * DIMM + kt + c8);
      *(uint4*)&Bs[r][c8] = *(const uint4*)(Bb + (size_t)r * DIMM + kt + c8);
    }
    __syncthreads();
    #pragma unroll
    for (int kk = 0; kk < 64; kk += 32) {
      bf16x8 af[4], bfr[4];
      #pragma unroll
      for (int i = 0; i < 4; ++i) af[i] = *(const bf16x8*)&As[wm + i * 16 + lr][kk + lk];
      #pragma unroll
      for (int j = 0; j < 4; ++j) bfr[j] = *(const bf16x8*)&Bs[wn + j * 16 + lr][kk + lk];
      #pragma unroll
      for (int i = 0; i < 4; ++i)
        #pragma unroll
        for (int j = 0; j < 4; ++j)
          acc[i][j] = __builtin_amdgcn_mfma_f32_16x16x32_bf16(af[i], bfr[j], acc[i][j], 0, 0, 0);
    }
  }

  const int rb = bm * 128 + wm + ((lane >> 4) << 2);
  const int cb = bn * 128 + wn + lr;
  #pragma unroll
  for (int i = 0; i < 4; ++i)
    #pragma unroll
    for (int j = 0; j < 4; ++j) {
      f32x4 v = acc[i][j];
      #pragma unroll
      for (int e = 0; e < 4; ++e)
        out[(size_t)(rb + i * 16 + e) * DIMM + cb + j * 16] = v[e];
    }
}

// ---------------- flash attention ----------------
// grid: 64 (b,h) x 16 Q-blocks of 128. 4 waves, each owns 32 Q rows. KVBLK=64.
__global__ __launch_bounds__(256) void attn(
    const ushort* __restrict__ q, const ushort* __restrict__ k,
    const ushort* __restrict__ vt, ushort* __restrict__ ao) {
  __shared__ ushort Ks[64][72];          // [n_kv][d]
  __shared__ ushort Vs[64][72];          // [d][n_kv]  (from transposed V)
  __shared__ ushort Ps[4][32][72];       // per-wave P tile [qrow][n_kv]

  const int tid = threadIdx.x;
  const int wid = tid >> 6, lane = tid & 63;
  const int lr = lane & 15, lk = (lane >> 4) * 8;
  const int bh = blockIdx.x >> 4;        // 0..63
  const int qb = blockIdx.x & 15;        // 0..15
  const size_t qk_base = (size_t)bh * SEQ * DHEAD;
  const size_t vt_base = (size_t)bh * DHEAD * SEQ;
  const int n0 = qb * 128 + wid * 32;

  // Q fragments in registers (q already scaled by 1/8)
  bf16x8 qf[2][2];
  #pragma unroll
  for (int mi = 0; mi < 2; ++mi)
    #pragma unroll
    for (int kk = 0; kk < 2; ++kk)
      qf[mi][kk] = *(const bf16x8*)(q + qk_base + (size_t)(n0 + mi * 16 + lr) * DHEAD + kk * 32 + lk);

  f32x4 acc_o[2][4] = {};
  float mrun[2][4], lrun[2][4];
  #pragma unroll
  for (int mi = 0; mi < 2; ++mi)
    #pragma unroll
    for (int j = 0; j < 4; ++j) { mrun[mi][j] = -1e30f; lrun[mi][j] = 0.f; }

  for (int ktile = 0; ktile < SEQ / 64; ++ktile) {
    __syncthreads();  // previous tile fully consumed
    #pragma unroll
    for (int p = 0; p < 2; ++p) {
      int e = p * 256 + tid;
      int r = e >> 3, c8 = (e & 7) << 3;
      *(uint4*)&Ks[r][c8] = *(const uint4*)(k + qk_base + (size_t)(ktile * 64 + r) * DHEAD + c8);
      *(uint4*)&Vs[r][c8] = *(const uint4*)(vt + vt_base + (size_t)r * SEQ + ktile * 64 + c8);
    }
    __syncthreads();

    // S = Q K^T  (acc_s[mi][nj]: rows mi*16+.., cols nj*16+..)
    f32x4 acc_s[2][4] = {};
    #pragma unroll
    for (int kk = 0; kk < 2; ++kk) {
      bf16x8 bk[4];
      #pragma unroll
      for (int nj = 0; nj < 4; ++nj)
        bk[nj] = *(const bf16x8*)&Ks[nj * 16 + lr][kk * 32 + lk];
      #pragma unroll
      for (int mi = 0; mi < 2; ++mi)
        #pragma unroll
        for (int nj = 0; nj < 4; ++nj)
          acc_s[mi][nj] = __builtin_amdgcn_mfma_f32_16x16x32_bf16(qf[mi][kk], bk[nj], acc_s[mi][nj], 0, 0, 0);
    }

    // online softmax; each lane co-owns rows (lane>>4)*4+j (+mi*16)
    float alpha[2][4];
    #pragma unroll
    for (int mi = 0; mi < 2; ++mi) {
      #pragma unroll
      for (int j = 0; j < 4; ++j) {
        float mx = fmaxf(fmaxf(acc_s[mi][0][j], acc_s[mi][1][j]),
                         fmaxf(acc_s[mi][2][j], acc_s[mi][3][j]));
        #pragma unroll
        for (int s = 1; s < 16; s <<= 1) mx = fmaxf(mx, __shfl_xor(mx, s, 64));
        float mnew = fmaxf(mrun[mi][j], mx);
        float a = __expf(mrun[mi][j] - mnew);
        mrun[mi][j] = mnew;
        float rs = 0.f;
        #pragma unroll
        for (int nj = 0; nj < 4; ++nj) {
          float p = __expf(acc_s[mi][nj][j] - mnew);
          Ps[wid][mi * 16 + ((lane >> 4) << 2) + j][nj * 16 + lr] = f2b(p);
          rs += p;
        }
        #pragma unroll
        for (int s = 1; s < 16; s <<= 1) rs += __shfl_xor(rs, s, 64);
        lrun[mi][j] = lrun[mi][j] * a + rs;
        alpha[mi][j] = a;
      }
    }
    // rescale O
    #pragma unroll
    for (int mi = 0; mi < 2; ++mi)
      #pragma unroll
      for (int db = 0; db < 4; ++db)
        #pragma unroll
        for (int e = 0; e < 4; ++e)
          acc_o[mi][db][e] *= alpha[mi][e];

    __syncthreads();  // P visible (and ordered) before PV reads

    // O += P @ V
    #pragma unroll
    for (int kk = 0; kk < 2; ++kk) {
      bf16x8 pa[2], bv[4];
      #pragma unroll
      for (int mi = 0; mi < 2; ++mi)
        pa[mi] = *(const bf16x8*)&Ps[wid][mi * 16 + lr][kk * 32 + lk];
      #pragma unroll
      for (int db = 0; db < 4; ++db)
        bv[db] = *(const bf16x8*)&Vs[db * 16 + lr][kk * 32 + lk];
      #pragma unroll
      for (int mi = 0; mi < 2; ++mi)
        #pragma unroll
        for (int db = 0; db < 4; ++db)
          acc_o[mi][db] = __builtin_amdgcn_mfma_f32_16x16x32_bf16(pa[mi], bv[db], acc_o[mi][db], 0, 0, 0);
    }
  }

  // epilogue: O / l, write ao[b][n][h*64+d]
  const int b = bh >> 3, h = bh & 7;
  #pragma unroll
  for (int mi = 0; mi < 2; ++mi)
    #pragma unroll
    for (int db = 0; db < 4; ++db) {
      #pragma unroll
      for (int e = 0; e < 4; ++e) {
        int nq = n0 + mi * 16 + ((lane >> 4) << 2) + e;
        int d = db * 16 + lr;
        float val = acc_o[mi][db][e] / lrun[mi][e];
        ao[((size_t)b * SEQ + nq) * DIMM + h * DHEAD + d] = f2b(val);
      }
    }
}

extern "C" void kernel_launch(void* const* d_in, const int* in_sizes, int n_in,
                              void* d_out, int out_size, void* d_ws, size_t ws_size,
                              hipStream_t stream) {
  const float* x = (const float*)d_in[0];
  const float* wqkv = (const float*)d_in[1];
  const float* wout = (const float*)d_in[2];
  float* out = (float*)d_out;

  char* ws = (char*)d_ws;
  const size_t SZ = (size_t)MTOT * DIMM * 2;  // 16 MB
  ushort* xb    = (ushort*)(ws);
  ushort* qw    = (ushort*)(ws + SZ);
  ushort* kw    = (ushort*)(ws + 2 * SZ);
  ushort* vtw   = (ushort*)(ws + 3 * SZ);
  ushort* aow   = (ushort*)(ws + 4 * SZ);
  ushort* wqkvT = (ushort*)(ws + 5 * SZ);
  ushort* woutT = (ushort*)(ws + 5 * SZ + (size_t)1536 * 512 * 2);

  hipLaunchKernelGGL(cvt_bf16, dim3(4096), dim3(256), 0, stream, x, xb, MTOT * DIMM / 8);
  hipLaunchKernelGGL(cvt_transpose, dim3(192), dim3(256), 0, stream, wqkv, wqkvT, 512, 1536);
  hipLaunchKernelGGL(cvt_transpose, dim3(64), dim3(256), 0, stream, wout, woutT, 512, 512);
  hipLaunchKernelGGL(gemm_qkv, dim3(128 * 12), dim3(256), 0, stream, xb, wqkvT, qw, kw, vtw);
  hipLaunchKernelGGL(attn, dim3(64 * 16), dim3(256), 0, stream, qw, kw, vtw, aow);
  hipLaunchKernelGGL(gemm_out, dim3(128 * 4), dim3(256), 0, stream, aow, woutT, out);
}

// Round 4
// 325.920 us; speedup vs baseline: 1.1888x; 1.1888x over previous
//
#include <hip/hip_runtime.h>
#include <hip/hip_bf16.h>
#include <stdint.h>

// Attention block: x@Wqkv -> flash-attn (8 heads, d=64, n=2048, b=8) -> @Wout
// bf16 MFMA (16x16x32) everywhere, fp32 accumulation.
// R4: attn overhead cuts — 2 barriers/tile (P is wave-private), async K/V
// stage (reg-carry), exp2-domain softmax (log2e folded into Q scale),
// defer-max rescale (THR=8).

#define NB 8
#define SEQ 2048
#define DIMM 512
#define HEADS 8
#define DHEAD 64
#define MTOT (NB * SEQ)  // 16384

typedef __attribute__((ext_vector_type(8))) short bf16x8;
typedef __attribute__((ext_vector_type(4))) float f32x4;

__device__ __forceinline__ ushort f2b(float f) {
  union { float f; uint32_t u; } c; c.f = f;
  return (ushort)((c.u + 0x7FFFu + ((c.u >> 16) & 1u)) >> 16);  // RNE
}

// ---------------- prep: fp32 -> bf16 (vectorized) ----------------
__global__ void cvt_bf16(const float* __restrict__ src, ushort* __restrict__ dst, int n8) {
  int i = blockIdx.x * blockDim.x + threadIdx.x;
  if (i >= n8) return;
  const float4* s = (const float4*)src;
  float4 a = s[2 * i], b = s[2 * i + 1];
  ushort o[8] = {f2b(a.x), f2b(a.y), f2b(a.z), f2b(a.w),
                 f2b(b.x), f2b(b.y), f2b(b.z), f2b(b.w)};
  *(uint4*)(dst + 8 * i) = *(const uint4*)o;
}

// ---------------- prep: fp32 [R][C] -> bf16 [C][R] ----------------
__global__ void cvt_transpose(const float* __restrict__ src, ushort* __restrict__ dst,
                              int R, int C) {
  __shared__ ushort tile[64][72];
  int nbc = C >> 6;
  int bc = blockIdx.x % nbc, br = blockIdx.x / nbc;
  int c0 = bc * 64, r0 = br * 64;
  #pragma unroll
  for (int p = 0; p < 16; ++p) {
    int e = p * 256 + threadIdx.x;
    int r = e >> 6, c = e & 63;
    tile[r][c] = f2b(src[(size_t)(r0 + r) * C + c0 + c]);
  }
  __syncthreads();
  #pragma unroll
  for (int p = 0; p < 16; ++p) {
    int e = p * 256 + threadIdx.x;
    int ct = e >> 6, rt = e & 63;
    dst[(size_t)(c0 + ct) * R + r0 + rt] = tile[rt][ct];
  }
}

// ---------------- GEMM: C[128][128]/block, A[m][k], Bt[n][k], K=512 ----------------
__global__ __launch_bounds__(256) void gemm_qkv(
    const ushort* __restrict__ A, const ushort* __restrict__ Bt,
    ushort* __restrict__ qo, ushort* __restrict__ ko, ushort* __restrict__ vto) {
  __shared__ ushort As[128][72];
  __shared__ ushort Bs[128][72];
  const int tid = threadIdx.x;
  const int bn = blockIdx.x % 12, bm = blockIdx.x / 12;
  const int wid = tid >> 6, lane = tid & 63;
  const int wm = (wid >> 1) * 64, wn = (wid & 1) * 64;
  const int lr = lane & 15, lk = (lane >> 4) * 8;

  f32x4 acc[4][4] = {};
  const ushort* Ab = A + (size_t)(bm * 128) * DIMM;
  const ushort* Bb = Bt + (size_t)(bn * 128) * DIMM;

  for (int kt = 0; kt < DIMM; kt += 64) {
    __syncthreads();
    #pragma unroll
    for (int p = 0; p < 4; ++p) {
      int e = p * 256 + tid;
      int r = e >> 3, c8 = (e & 7) << 3;
      *(uint4*)&As[r][c8] = *(const uint4*)(Ab + (size_t)r * DIMM + kt + c8);
      *(uint4*)&Bs[r][c8] = *(const uint4*)(Bb + (size_t)r * DIMM + kt + c8);
    }
    __syncthreads();
    #pragma unroll
    for (int kk = 0; kk < 64; kk += 32) {
      bf16x8 af[4], bfr[4];
      #pragma unroll
      for (int i = 0; i < 4; ++i) af[i] = *(const bf16x8*)&As[wm + i * 16 + lr][kk + lk];
      #pragma unroll
      for (int j = 0; j < 4; ++j) bfr[j] = *(const bf16x8*)&Bs[wn + j * 16 + lr][kk + lk];
      #pragma unroll
      for (int i = 0; i < 4; ++i)
        #pragma unroll
        for (int j = 0; j < 4; ++j)
          acc[i][j] = __builtin_amdgcn_mfma_f32_16x16x32_bf16(af[i], bfr[j], acc[i][j], 0, 0, 0);
    }
  }

  const int rb = bm * 128 + wm + ((lane >> 4) << 2);
  const int cb = bn * 128 + wn + lr;
  // q scale: 1/sqrt(64) * log2(e)  (softmax runs in exp2 domain)
  const float QSCALE = 0.125f * 1.44269504f;
  #pragma unroll
  for (int i = 0; i < 4; ++i) {
    #pragma unroll
    for (int j = 0; j < 4; ++j) {
      int col = cb + j * 16;
      int t = col >> 9, h = (col >> 6) & 7, d = col & 63;
      f32x4 v = acc[i][j];
      #pragma unroll
      for (int e = 0; e < 4; ++e) {
        int row = rb + i * 16 + e;
        int b = row >> 11, n = row & 2047;
        float val = v[e];
        if (t == 0) {
          qo[(((size_t)b * HEADS + h) * SEQ + n) * DHEAD + d] = f2b(val * QSCALE);
        } else if (t == 1) {
          ko[(((size_t)b * HEADS + h) * SEQ + n) * DHEAD + d] = f2b(val);
        } else {
          vto[(((size_t)b * HEADS + h) * DHEAD + d) * SEQ + n] = f2b(val);  // V transposed
        }
      }
    }
  }
}

__global__ __launch_bounds__(256) void gemm_out(
    const ushort* __restrict__ A, const ushort* __restrict__ Bt, float* __restrict__ out) {
  __shared__ ushort As[128][72];
  __shared__ ushort Bs[128][72];
  const int tid = threadIdx.x;
  const int bn = blockIdx.x % 4, bm = blockIdx.x / 4;
  const int wid = tid >> 6, lane = tid & 63;
  const int wm = (wid >> 1) * 64, wn = (wid & 1) * 64;
  const int lr = lane & 15, lk = (lane >> 4) * 8;

  f32x4 acc[4][4] = {};
  const ushort* Ab = A + (size_t)(bm * 128) * DIMM;
  const ushort* Bb = Bt + (size_t)(bn * 128) * DIMM;

  for (int kt = 0; kt < DIMM; kt += 64) {
    __syncthreads();
    #pragma unroll
    for (int p = 0; p < 4; ++p) {
      int e = p * 256 + tid;
      int r = e >> 3, c8 = (e & 7) << 3;
      *(uint4*)&As[r][c8] = *(const uint4*)(Ab + (size_t)r * DIMM + kt + c8);
      *(uint4*)&Bs[r][c8] = *(const uint4*)(Bb + (size_t)r * DIMM + kt + c8);
    }
    __syncthreads();
    #pragma unroll
    for (int kk = 0; kk < 64; kk += 32) {
      bf16x8 af[4], bfr[4];
      #pragma unroll
      for (int i = 0; i < 4; ++i) af[i] = *(const bf16x8*)&As[wm + i * 16 + lr][kk + lk];
      #pragma unroll
      for (int j = 0; j < 4; ++j) bfr[j] = *(const bf16x8*)&Bs[wn + j * 16 + lr][kk + lk];
      #pragma unroll
      for (int i = 0; i < 4; ++i)
        #pragma unroll
        for (int j = 0; j < 4; ++j)
          acc[i][j] = __builtin_amdgcn_mfma_f32_16x16x32_bf16(af[i], bfr[j], acc[i][j], 0, 0, 0);
    }
  }

  const int rb = bm * 128 + wm + ((lane >> 4) << 2);
  const int cb = bn * 128 + wn + lr;
  #pragma unroll
  for (int i = 0; i < 4; ++i)
    #pragma unroll
    for (int j = 0; j < 4; ++j) {
      f32x4 v = acc[i][j];
      #pragma unroll
      for (int e = 0; e < 4; ++e)
        out[(size_t)(rb + i * 16 + e) * DIMM + cb + j * 16] = v[e];
    }
}

// ---------------- flash attention ----------------
// grid: 64 (b,h) x 16 Q-blocks of 128. 4 waves, each owns 32 Q rows. KVBLK=64.
// 2 barriers/tile; K/V staged via registers one tile ahead (latency hidden
// under compute); softmax in exp2 domain; defer-max rescale.
__global__ __launch_bounds__(256) void attn(
    const ushort* __restrict__ q, const ushort* __restrict__ k,
    const ushort* __restrict__ vt, ushort* __restrict__ ao) {
  __shared__ ushort Ks[64][72];          // [n_kv][d]
  __shared__ ushort Vs[64][72];          // [d][n_kv]
  __shared__ ushort Ps[4][32][72];       // per-wave P tile [qrow][n_kv]

  const int tid = threadIdx.x;
  const int wid = tid >> 6, lane = tid & 63;
  const int lr = lane & 15, lk = (lane >> 4) * 8;
  const int bh = blockIdx.x >> 4;
  const int qb = blockIdx.x & 15;
  const size_t qk_base = (size_t)bh * SEQ * DHEAD;
  const size_t vt_base = (size_t)bh * DHEAD * SEQ;
  const int n0 = qb * 128 + wid * 32;

  // staging coords: thread covers rows r0 and r0+32, 16B at col c0
  const int r0 = tid >> 3, c0 = (tid & 7) << 3;
  const int r1 = r0 + 32;

  bf16x8 qf[2][2];
  #pragma unroll
  for (int mi = 0; mi < 2; ++mi)
    #pragma unroll
    for (int kk = 0; kk < 2; ++kk)
      qf[mi][kk] = *(const bf16x8*)(q + qk_base + (size_t)(n0 + mi * 16 + lr) * DHEAD + kk * 32 + lk);

  f32x4 acc_o[2][4] = {};
  float mrun[2][4], lrun[2][4];
  #pragma unroll
  for (int mi = 0; mi < 2; ++mi)
    #pragma unroll
    for (int j = 0; j < 4; ++j) { mrun[mi][j] = -1e30f; lrun[mi][j] = 0.f; }

  // preload tile 0 into registers
  uint4 kreg0 = *(const uint4*)(k + qk_base + (size_t)r0 * DHEAD + c0);
  uint4 kreg1 = *(const uint4*)(k + qk_base + (size_t)r1 * DHEAD + c0);
  uint4 vreg0 = *(const uint4*)(vt + vt_base + (size_t)r0 * SEQ + c0);
  uint4 vreg1 = *(const uint4*)(vt + vt_base + (size_t)r1 * SEQ + c0);

  for (int t = 0; t < SEQ / 64; ++t) {
    __syncthreads();  // all waves done reading previous tile's LDS
    *(uint4*)&Ks[r0][c0] = kreg0;
    *(uint4*)&Ks[r1][c0] = kreg1;
    *(uint4*)&Vs[r0][c0] = vreg0;
    *(uint4*)&Vs[r1][c0] = vreg1;
    __syncthreads();

    // issue next tile's loads — latency hides under this tile's compute
    if (t + 1 < SEQ / 64) {
      int nt = (t + 1) * 64;
      kreg0 = *(const uint4*)(k + qk_base + (size_t)(nt + r0) * DHEAD + c0);
      kreg1 = *(const uint4*)(k + qk_base + (size_t)(nt + r1) * DHEAD + c0);
      vreg0 = *(const uint4*)(vt + vt_base + (size_t)r0 * SEQ + nt + c0);
      vreg1 = *(const uint4*)(vt + vt_base + (size_t)r1 * SEQ + nt + c0);
    }

    // S = Q K^T (exp2 domain; q pre-scaled by 1/8*log2e)
    f32x4 acc_s[2][4] = {};
    #pragma unroll
    for (int kk = 0; kk < 2; ++kk) {
      bf16x8 bk[4];
      #pragma unroll
      for (int nj = 0; nj < 4; ++nj)
        bk[nj] = *(const bf16x8*)&Ks[nj * 16 + lr][kk * 32 + lk];
      #pragma unroll
      for (int mi = 0; mi < 2; ++mi)
        #pragma unroll
        for (int nj = 0; nj < 4; ++nj)
          acc_s[mi][nj] = __builtin_amdgcn_mfma_f32_16x16x32_bf16(qf[mi][kk], bk[nj], acc_s[mi][nj], 0, 0, 0);
    }

    // row maxes (each lane co-owns rows (lane>>4)*4+j, +mi*16)
    float mx[2][4];
    #pragma unroll
    for (int mi = 0; mi < 2; ++mi)
      #pragma unroll
      for (int j = 0; j < 4; ++j) {
        float m0 = fmaxf(fmaxf(acc_s[mi][0][j], acc_s[mi][1][j]),
                         fmaxf(acc_s[mi][2][j], acc_s[mi][3][j]));
        #pragma unroll
        for (int s = 1; s < 16; s <<= 1) m0 = fmaxf(m0, __shfl_xor(m0, s, 64));
        mx[mi][j] = m0;
      }

    // defer-max: only rescale when some row max grew by > 8 (exp2 domain)
    float g = -1e30f;
    #pragma unroll
    for (int mi = 0; mi < 2; ++mi)
      #pragma unroll
      for (int j = 0; j < 4; ++j) g = fmaxf(g, mx[mi][j] - mrun[mi][j]);
    if (__any(g > 8.0f)) {
      float alpha[2][4];
      #pragma unroll
      for (int mi = 0; mi < 2; ++mi)
        #pragma unroll
        for (int j = 0; j < 4; ++j) {
          float mnew = fmaxf(mrun[mi][j], mx[mi][j]);
          alpha[mi][j] = exp2f(mrun[mi][j] - mnew);
          mrun[mi][j] = mnew;
          lrun[mi][j] *= alpha[mi][j];
        }
      #pragma unroll
      for (int mi = 0; mi < 2; ++mi)
        #pragma unroll
        for (int db = 0; db < 4; ++db)
          #pragma unroll
          for (int e = 0; e < 4; ++e)
            acc_o[mi][db][e] *= alpha[mi][e];
    }

    // P = exp2(S - m), row sums
    #pragma unroll
    for (int mi = 0; mi < 2; ++mi)
      #pragma unroll
      for (int j = 0; j < 4; ++j) {
        float rs = 0.f;
        #pragma unroll
        for (int nj = 0; nj < 4; ++nj) {
          float p = exp2f(acc_s[mi][nj][j] - mrun[mi][j]);
          Ps[wid][mi * 16 + ((lane >> 4) << 2) + j][nj * 16 + lr] = f2b(p);
          rs += p;
        }
        #pragma unroll
        for (int s = 1; s < 16; s <<= 1) rs += __shfl_xor(rs, s, 64);
        lrun[mi][j] += rs;
      }

    // no barrier: Ps is wave-private (same-wave DS ordering), Vs unchanged
    // O += P @ V
    #pragma unroll
    for (int kk = 0; kk < 2; ++kk) {
      bf16x8 pa[2], bv[4];
      #pragma unroll
      for (int mi = 0; mi < 2; ++mi)
        pa[mi] = *(const bf16x8*)&Ps[wid][mi * 16 + lr][kk * 32 + lk];
      #pragma unroll
      for (int db = 0; db < 4; ++db)
        bv[db] = *(const bf16x8*)&Vs[db * 16 + lr][kk * 32 + lk];
      #pragma unroll
      for (int mi = 0; mi < 2; ++mi)
        #pragma unroll
        for (int db = 0; db < 4; ++db)
          acc_o[mi][db] = __builtin_amdgcn_mfma_f32_16x16x32_bf16(pa[mi], bv[db], acc_o[mi][db], 0, 0, 0);
    }
  }

  // epilogue: O / l -> ao[b][n][h*64+d]
  const int b = bh >> 3, h = bh & 7;
  #pragma unroll
  for (int mi = 0; mi < 2; ++mi)
    #pragma unroll
    for (int db = 0; db < 4; ++db) {
      #pragma unroll
      for (int e = 0; e < 4; ++e) {
        int nq = n0 + mi * 16 + ((lane >> 4) << 2) + e;
        int d = db * 16 + lr;
        float val = acc_o[mi][db][e] / lrun[mi][e];
        ao[((size_t)b * SEQ + nq) * DIMM + h * DHEAD + d] = f2b(val);
      }
    }
}

extern "C" void kernel_launch(void* const* d_in, const int* in_sizes, int n_in,
                              void* d_out, int out_size, void* d_ws, size_t ws_size,
                              hipStream_t stream) {
  const float* x = (const float*)d_in[0];
  const float* wqkv = (const float*)d_in[1];
  const float* wout = (const float*)d_in[2];
  float* out = (float*)d_out;

  char* ws = (char*)d_ws;
  const size_t SZ = (size_t)MTOT * DIMM * 2;  // 16 MB
  ushort* xb    = (ushort*)(ws);
  ushort* qw    = (ushort*)(ws + SZ);
  ushort* kw    = (ushort*)(ws + 2 * SZ);
  ushort* vtw   = (ushort*)(ws + 3 * SZ);
  ushort* aow   = (ushort*)(ws + 4 * SZ);
  ushort* wqkvT = (ushort*)(ws + 5 * SZ);
  ushort* woutT = (ushort*)(ws + 5 * SZ + (size_t)1536 * 512 * 2);

  hipLaunchKernelGGL(cvt_bf16, dim3(4096), dim3(256), 0, stream, x, xb, MTOT * DIMM / 8);
  hipLaunchKernelGGL(cvt_transpose, dim3(192), dim3(256), 0, stream, wqkv, wqkvT, 512, 1536);
  hipLaunchKernelGGL(cvt_transpose, dim3(64), dim3(256), 0, stream, wout, woutT, 512, 512);
  hipLaunchKernelGGL(gemm_qkv, dim3(128 * 12), dim3(256), 0, stream, xb, wqkvT, qw, kw, vtw);
  hipLaunchKernelGGL(attn, dim3(64 * 16), dim3(256), 0, stream, qw, kw, vtw, aow);
  hipLaunchKernelGGL(gemm_out, dim3(128 * 4), dim3(256), 0, stream, aow, woutT, out);
}

// Round 5
// 201.101 us; speedup vs baseline: 1.9267x; 1.6207x over previous
//
#include <hip/hip_runtime.h>
#include <hip/hip_bf16.h>
#include <stdint.h>

// Attention block: x@Wqkv -> flash-attn (8 heads, d=64, n=2048, b=8) -> @Wout
// R5: attn restructured to swapped-operand 32x32x16 MFMA (S^T = K.Q^T) with
// lane-local softmax, cvt_pk+permlane32_swap P packing (no P LDS), XOR-swizzled
// K/V tiles. GEMMs unchanged (validated).

#define NB 8
#define SEQ 2048
#define DIMM 512
#define HEADS 8
#define DHEAD 64
#define MTOT (NB * SEQ)  // 16384

typedef __attribute__((ext_vector_type(8))) short bf16x8;
typedef __attribute__((ext_vector_type(4))) float f32x4;
typedef __attribute__((ext_vector_type(16))) float f32x16;
typedef __attribute__((ext_vector_type(4))) uint u32x4;

__device__ __forceinline__ ushort f2b(float f) {
  union { float f; uint32_t u; } c; c.f = f;
  return (ushort)((c.u + 0x7FFFu + ((c.u >> 16) & 1u)) >> 16);  // RNE
}

__device__ __forceinline__ uint cvtpk(float lo, float hi) {
  uint r;
  asm("v_cvt_pk_bf16_f32 %0, %1, %2" : "=v"(r) : "v"(lo), "v"(hi));
  return r;
}
// v_permlane32_swap_b32: a.hi32lanes <-> b.lo32lanes.
// After: a = data originating from lanes 0-31 (a's for lo, b's for hi);
//        b = data originating from lanes 32-63.
__device__ __forceinline__ void plswap(uint& a, uint& b) {
  asm("v_permlane32_swap_b32 %0, %1" : "+v"(a), "+v"(b));
}
__device__ __forceinline__ bf16x8 mk8(uint a, uint b, uint c, uint d) {
  u32x4 t = {a, b, c, d};
  return __builtin_bit_cast(bf16x8, t);
}

// ---------------- prep: fp32 -> bf16 (vectorized) ----------------
__global__ void cvt_bf16(const float* __restrict__ src, ushort* __restrict__ dst, int n8) {
  int i = blockIdx.x * blockDim.x + threadIdx.x;
  if (i >= n8) return;
  const float4* s = (const float4*)src;
  float4 a = s[2 * i], b = s[2 * i + 1];
  ushort o[8] = {f2b(a.x), f2b(a.y), f2b(a.z), f2b(a.w),
                 f2b(b.x), f2b(b.y), f2b(b.z), f2b(b.w)};
  *(uint4*)(dst + 8 * i) = *(const uint4*)o;
}

// ---------------- prep: fp32 [R][C] -> bf16 [C][R] ----------------
__global__ void cvt_transpose(const float* __restrict__ src, ushort* __restrict__ dst,
                              int R, int C) {
  __shared__ ushort tile[64][72];
  int nbc = C >> 6;
  int bc = blockIdx.x % nbc, br = blockIdx.x / nbc;
  int c0 = bc * 64, r0 = br * 64;
  #pragma unroll
  for (int p = 0; p < 16; ++p) {
    int e = p * 256 + threadIdx.x;
    int r = e >> 6, c = e & 63;
    tile[r][c] = f2b(src[(size_t)(r0 + r) * C + c0 + c]);
  }
  __syncthreads();
  #pragma unroll
  for (int p = 0; p < 16; ++p) {
    int e = p * 256 + threadIdx.x;
    int ct = e >> 6, rt = e & 63;
    dst[(size_t)(c0 + ct) * R + r0 + rt] = tile[rt][ct];
  }
}

// ---------------- GEMM: C[128][128]/block, A[m][k], Bt[n][k], K=512 ----------------
__global__ __launch_bounds__(256) void gemm_qkv(
    const ushort* __restrict__ A, const ushort* __restrict__ Bt,
    ushort* __restrict__ qo, ushort* __restrict__ ko, ushort* __restrict__ vto) {
  __shared__ ushort As[128][72];
  __shared__ ushort Bs[128][72];
  const int tid = threadIdx.x;
  const int bn = blockIdx.x % 12, bm = blockIdx.x / 12;
  const int wid = tid >> 6, lane = tid & 63;
  const int wm = (wid >> 1) * 64, wn = (wid & 1) * 64;
  const int lr = lane & 15, lk = (lane >> 4) * 8;

  f32x4 acc[4][4] = {};
  const ushort* Ab = A + (size_t)(bm * 128) * DIMM;
  const ushort* Bb = Bt + (size_t)(bn * 128) * DIMM;

  for (int kt = 0; kt < DIMM; kt += 64) {
    __syncthreads();
    #pragma unroll
    for (int p = 0; p < 4; ++p) {
      int e = p * 256 + tid;
      int r = e >> 3, c8 = (e & 7) << 3;
      *(uint4*)&As[r][c8] = *(const uint4*)(Ab + (size_t)r * DIMM + kt + c8);
      *(uint4*)&Bs[r][c8] = *(const uint4*)(Bb + (size_t)r * DIMM + kt + c8);
    }
    __syncthreads();
    #pragma unroll
    for (int kk = 0; kk < 64; kk += 32) {
      bf16x8 af[4], bfr[4];
      #pragma unroll
      for (int i = 0; i < 4; ++i) af[i] = *(const bf16x8*)&As[wm + i * 16 + lr][kk + lk];
      #pragma unroll
      for (int j = 0; j < 4; ++j) bfr[j] = *(const bf16x8*)&Bs[wn + j * 16 + lr][kk + lk];
      #pragma unroll
      for (int i = 0; i < 4; ++i)
        #pragma unroll
        for (int j = 0; j < 4; ++j)
          acc[i][j] = __builtin_amdgcn_mfma_f32_16x16x32_bf16(af[i], bfr[j], acc[i][j], 0, 0, 0);
    }
  }

  const int rb = bm * 128 + wm + ((lane >> 4) << 2);
  const int cb = bn * 128 + wn + lr;
  // q scale: 1/sqrt(64) * log2(e)  (softmax runs in exp2 domain)
  const float QSCALE = 0.125f * 1.44269504f;
  #pragma unroll
  for (int i = 0; i < 4; ++i) {
    #pragma unroll
    for (int j = 0; j < 4; ++j) {
      int col = cb + j * 16;
      int t = col >> 9, h = (col >> 6) & 7, d = col & 63;
      f32x4 v = acc[i][j];
      #pragma unroll
      for (int e = 0; e < 4; ++e) {
        int row = rb + i * 16 + e;
        int b = row >> 11, n = row & 2047;
        float val = v[e];
        if (t == 0) {
          qo[(((size_t)b * HEADS + h) * SEQ + n) * DHEAD + d] = f2b(val * QSCALE);
        } else if (t == 1) {
          ko[(((size_t)b * HEADS + h) * SEQ + n) * DHEAD + d] = f2b(val);
        } else {
          vto[(((size_t)b * HEADS + h) * DHEAD + d) * SEQ + n] = f2b(val);  // V transposed
        }
      }
    }
  }
}

__global__ __launch_bounds__(256) void gemm_out(
    const ushort* __restrict__ A, const ushort* __restrict__ Bt, float* __restrict__ out) {
  __shared__ ushort As[128][72];
  __shared__ ushort Bs[128][72];
  const int tid = threadIdx.x;
  const int bn = blockIdx.x % 4, bm = blockIdx.x / 4;
  const int wid = tid >> 6, lane = tid & 63;
  const int wm = (wid >> 1) * 64, wn = (wid & 1) * 64;
  const int lr = lane & 15, lk = (lane >> 4) * 8;

  f32x4 acc[4][4] = {};
  const ushort* Ab = A + (size_t)(bm * 128) * DIMM;
  const ushort* Bb = Bt + (size_t)(bn * 128) * DIMM;

  for (int kt = 0; kt < DIMM; kt += 64) {
    __syncthreads();
    #pragma unroll
    for (int p = 0; p < 4; ++p) {
      int e = p * 256 + tid;
      int r = e >> 3, c8 = (e & 7) << 3;
      *(uint4*)&As[r][c8] = *(const uint4*)(Ab + (size_t)r * DIMM + kt + c8);
      *(uint4*)&Bs[r][c8] = *(const uint4*)(Bb + (size_t)r * DIMM + kt + c8);
    }
    __syncthreads();
    #pragma unroll
    for (int kk = 0; kk < 64; kk += 32) {
      bf16x8 af[4], bfr[4];
      #pragma unroll
      for (int i = 0; i < 4; ++i) af[i] = *(const bf16x8*)&As[wm + i * 16 + lr][kk + lk];
      #pragma unroll
      for (int j = 0; j < 4; ++j) bfr[j] = *(const bf16x8*)&Bs[wn + j * 16 + lr][kk + lk];
      #pragma unroll
      for (int i = 0; i < 4; ++i)
        #pragma unroll
        for (int j = 0; j < 4; ++j)
          acc[i][j] = __builtin_amdgcn_mfma_f32_16x16x32_bf16(af[i], bfr[j], acc[i][j], 0, 0, 0);
    }
  }

  const int rb = bm * 128 + wm + ((lane >> 4) << 2);
  const int cb = bn * 128 + wn + lr;
  #pragma unroll
  for (int i = 0; i < 4; ++i)
    #pragma unroll
    for (int j = 0; j < 4; ++j) {
      f32x4 v = acc[i][j];
      #pragma unroll
      for (int e = 0; e < 4; ++e)
        out[(size_t)(rb + i * 16 + e) * DIMM + cb + j * 16] = v[e];
    }
}

// ---------------- flash attention (swapped-operand 32x32) ----------------
// grid: 64 (b,h) x 16 Q-blocks of 128. 4 waves x 32 q-rows. KVBLK=64.
// S^T = mfma32(K, Q^T): lane holds q=l&31 col; kv rows (reg&3)+8(reg>>2)+4(l>>5)
// per 32-row block. O^T = mfma32(V^T, P^T) accumulated the same way.
// K/V tiles in LDS, XOR-swizzled (16B slot ^= row&7) -> conflict-free frag reads.
__global__ __launch_bounds__(256) void attn(
    const ushort* __restrict__ q, const ushort* __restrict__ k,
    const ushort* __restrict__ vt, ushort* __restrict__ ao) {
  __shared__ ushort Ks[64 * 64];   // [kv][d], swizzled
  __shared__ ushort Vs[64 * 64];   // [d][kv], swizzled

  const int tid = threadIdx.x;
  const int wid = tid >> 6, l = tid & 63;
  const int l31 = l & 31, hi = l >> 5;
  const int bh = blockIdx.x >> 4, qb = blockIdx.x & 15;
  const ushort* kb = k + (size_t)bh * SEQ * DHEAD;
  const ushort* vb = vt + (size_t)bh * DHEAD * SEQ;
  const int nq = qb * 128 + wid * 32 + l31;

  // Q B-fragments: lane needs Q[q=l31-row][d = ks*16 + hi*8 .. +7]
  bf16x8 qf[4];
  const ushort* qrow = q + (size_t)bh * SEQ * DHEAD + (size_t)nq * DHEAD;
  #pragma unroll
  for (int ks = 0; ks < 4; ++ks)
    qf[ks] = *(const bf16x8*)(qrow + ks * 16 + hi * 8);

  f32x16 accO0 = {}, accO1 = {};   // O^T rows d = dd*32 + (r&3)+8(r>>2)+4hi
  float mrun = -1e30f, lrun = 0.f;

  // staging: thread covers rows sr, sr+32; 16B at slot sc (linear global read,
  // swizzled LDS write)
  const int sr = tid >> 3, sc = tid & 7;
  const int swz = (sc ^ (sr & 7)) << 3;   // (sr+32)&7 == sr&7
  uint4 k0 = *(const uint4*)(kb + (size_t)sr * DHEAD + sc * 8);
  uint4 k1 = *(const uint4*)(kb + (size_t)(sr + 32) * DHEAD + sc * 8);
  uint4 v0 = *(const uint4*)(vb + (size_t)sr * SEQ + sc * 8);
  uint4 v1 = *(const uint4*)(vb + (size_t)(sr + 32) * SEQ + sc * 8);

  const int fsx = (l31 & 7);   // row&7 for frag reads (same for row and row+32)

  for (int t = 0; t < SEQ / 64; ++t) {
    __syncthreads();  // previous tile fully consumed
    *(uint4*)&Ks[sr * 64 + swz] = k0;
    *(uint4*)&Ks[(sr + 32) * 64 + swz] = k1;
    *(uint4*)&Vs[sr * 64 + swz] = v0;
    *(uint4*)&Vs[(sr + 32) * 64 + swz] = v1;
    __syncthreads();

    // async: issue next tile's global loads (hide under compute)
    if (t + 1 < SEQ / 64) {
      int nt = (t + 1) * 64;
      k0 = *(const uint4*)(kb + (size_t)(nt + sr) * DHEAD + sc * 8);
      k1 = *(const uint4*)(kb + (size_t)(nt + sr + 32) * DHEAD + sc * 8);
      v0 = *(const uint4*)(vb + (size_t)sr * SEQ + nt + sc * 8);
      v1 = *(const uint4*)(vb + (size_t)(sr + 32) * SEQ + nt + sc * 8);
    }

    // S^T = K . Q^T   (two 32-kv blocks)
    f32x16 s0 = {}, s1 = {};
    #pragma unroll
    for (int ks = 0; ks < 4; ++ks) {
      int g = (ks << 1) | hi;
      int so = (g ^ fsx) << 3;
      bf16x8 kf0 = *(const bf16x8*)&Ks[l31 * 64 + so];
      bf16x8 kf1 = *(const bf16x8*)&Ks[(32 + l31) * 64 + so];
      s0 = __builtin_amdgcn_mfma_f32_32x32x16_bf16(kf0, qf[ks], s0, 0, 0, 0);
      s1 = __builtin_amdgcn_mfma_f32_32x32x16_bf16(kf1, qf[ks], s1, 0, 0, 0);
    }

    // lane-local row max (q row = l31; partner lane^32 has other 32 kv)
    float mx = s0[0];
    #pragma unroll
    for (int i = 1; i < 16; ++i) mx = fmaxf(mx, s0[i]);
    #pragma unroll
    for (int i = 0; i < 16; ++i) mx = fmaxf(mx, s1[i]);
    mx = fmaxf(mx, __shfl_xor(mx, 32));

    // defer-max: rescale only when max grew > 8 (exp2 domain; P <= 256)
    if (__any(mx - mrun > 8.0f)) {
      float mnew = fmaxf(mrun, mx);
      float alpha = __builtin_amdgcn_exp2f(mrun - mnew);
      mrun = mnew;
      lrun *= alpha;
      #pragma unroll
      for (int i = 0; i < 16; ++i) { accO0[i] *= alpha; accO1[i] *= alpha; }
    }

    // P = exp2(S - m), row sum
    float rs = 0.f;
    #pragma unroll
    for (int i = 0; i < 16; ++i) {
      s0[i] = __builtin_amdgcn_exp2f(s0[i] - mrun); rs += s0[i];
      s1[i] = __builtin_amdgcn_exp2f(s1[i] - mrun); rs += s1[i];
    }
    rs += __shfl_xor(rs, 32);
    lrun += rs;

    // pack P^T B-fragments: per kv-16-slice, cvt_pk pairs + permlane32_swap.
    // pf[kk] holds kv = kk*16 + hi*8 + [0..7] for col q=l31.
    bf16x8 pf0, pf1, pf2, pf3;
    {
      uint a0 = cvtpk(s0[0], s0[1]),  a1 = cvtpk(s0[2], s0[3]);
      uint b0 = cvtpk(s0[4], s0[5]),  b1 = cvtpk(s0[6], s0[7]);
      plswap(a0, b0); plswap(a1, b1);
      pf0 = mk8(a0, a1, b0, b1);
      a0 = cvtpk(s0[8], s0[9]);   a1 = cvtpk(s0[10], s0[11]);
      b0 = cvtpk(s0[12], s0[13]); b1 = cvtpk(s0[14], s0[15]);
      plswap(a0, b0); plswap(a1, b1);
      pf1 = mk8(a0, a1, b0, b1);
      a0 = cvtpk(s1[0], s1[1]);   a1 = cvtpk(s1[2], s1[3]);
      b0 = cvtpk(s1[4], s1[5]);   b1 = cvtpk(s1[6], s1[7]);
      plswap(a0, b0); plswap(a1, b1);
      pf2 = mk8(a0, a1, b0, b1);
      a0 = cvtpk(s1[8], s1[9]);   a1 = cvtpk(s1[10], s1[11]);
      b0 = cvtpk(s1[12], s1[13]); b1 = cvtpk(s1[14], s1[15]);
      plswap(a0, b0); plswap(a1, b1);
      pf3 = mk8(a0, a1, b0, b1);
    }

    // O^T += V^T . P^T
    #pragma unroll
    for (int kk = 0; kk < 4; ++kk) {
      int g = (kk << 1) | hi;
      int so = (g ^ fsx) << 3;
      bf16x8 vf0 = *(const bf16x8*)&Vs[l31 * 64 + so];
      bf16x8 vf1 = *(const bf16x8*)&Vs[(32 + l31) * 64 + so];
      bf16x8 pk = (kk == 0) ? pf0 : (kk == 1) ? pf1 : (kk == 2) ? pf2 : pf3;
      accO0 = __builtin_amdgcn_mfma_f32_32x32x16_bf16(vf0, pk, accO0, 0, 0, 0);
      accO1 = __builtin_amdgcn_mfma_f32_32x32x16_bf16(vf1, pk, accO1, 0, 0, 0);
    }
  }

  // epilogue: O = accO / lrun; write ao[b][n=q][h*64 + d]
  const int b = bh >> 3, h = bh & 7;
  const float rl = 1.0f / lrun;
  ushort* aop = ao + ((size_t)b * SEQ + nq) * DIMM + h * DHEAD;
  #pragma unroll
  for (int gq = 0; gq < 4; ++gq) {
    // dd=0
    {
      int d0 = 8 * gq + 4 * hi;
      uint u0 = (uint)f2b(accO0[4 * gq + 0] * rl) | ((uint)f2b(accO0[4 * gq + 1] * rl) << 16);
      uint u1 = (uint)f2b(accO0[4 * gq + 2] * rl) | ((uint)f2b(accO0[4 * gq + 3] * rl) << 16);
      *(uint2*)(aop + d0) = make_uint2(u0, u1);
    }
    // dd=1
    {
      int d0 = 32 + 8 * gq + 4 * hi;
      uint u0 = (uint)f2b(accO1[4 * gq + 0] * rl) | ((uint)f2b(accO1[4 * gq + 1] * rl) << 16);
      uint u1 = (uint)f2b(accO1[4 * gq + 2] * rl) | ((uint)f2b(accO1[4 * gq + 3] * rl) << 16);
      *(uint2*)(aop + d0) = make_uint2(u0, u1);
    }
  }
}

extern "C" void kernel_launch(void* const* d_in, const int* in_sizes, int n_in,
                              void* d_out, int out_size, void* d_ws, size_t ws_size,
                              hipStream_t stream) {
  const float* x = (const float*)d_in[0];
  const float* wqkv = (const float*)d_in[1];
  const float* wout = (const float*)d_in[2];
  float* out = (float*)d_out;

  char* ws = (char*)d_ws;
  const size_t SZ = (size_t)MTOT * DIMM * 2;  // 16 MB
  ushort* xb    = (ushort*)(ws);
  ushort* qw    = (ushort*)(ws + SZ);
  ushort* kw    = (ushort*)(ws + 2 * SZ);
  ushort* vtw   = (ushort*)(ws + 3 * SZ);
  ushort* aow   = (ushort*)(ws + 4 * SZ);
  ushort* wqkvT = (ushort*)(ws + 5 * SZ);
  ushort* woutT = (ushort*)(ws + 5 * SZ + (size_t)1536 * 512 * 2);

  hipLaunchKernelGGL(cvt_bf16, dim3(4096), dim3(256), 0, stream, x, xb, MTOT * DIMM / 8);
  hipLaunchKernelGGL(cvt_transpose, dim3(192), dim3(256), 0, stream, wqkv, wqkvT, 512, 1536);
  hipLaunchKernelGGL(cvt_transpose, dim3(64), dim3(256), 0, stream, wout, woutT, 512, 512);
  hipLaunchKernelGGL(gemm_qkv, dim3(128 * 12), dim3(256), 0, stream, xb, wqkvT, qw, kw, vtw);
  hipLaunchKernelGGL(attn, dim3(64 * 16), dim3(256), 0, stream, qw, kw, vtw, aow);
  hipLaunchKernelGGL(gemm_out, dim3(128 * 4), dim3(256), 0, stream, aow, woutT, out);
}